// Round 1
// 12080.560 us; speedup vs baseline: 1.7811x; 1.7811x over previous
//
#include <hip/hip_runtime.h>
#include <hip/hip_fp16.h>

#define T_LEN 2048
#define HID   2048
#define G4    8192
#define NV    128

typedef _Float16 h2_t __attribute__((ext_vector_type(2)));

__device__ __forceinline__ float uph(unsigned u) {
  return __half2float(__ushort_as_half((unsigned short)(u & 0xffffu)));
}
__device__ __forceinline__ unsigned pkh(float h, unsigned tag) {
  return (tag << 16) | (unsigned)__half_as_ushort(__float2half_rn(h));
}
__device__ __forceinline__ h2_t pk2(float a, float bb) {
  return __builtin_bit_cast(h2_t, __builtin_amdgcn_cvt_pkrtz(a, bb));
}

// Coherent (cache-bypassing) 16B load — 4 tagged elements per transaction.
__device__ __forceinline__ uint4 ld_sc16(const unsigned* p) {
  uint4 r;
  asm volatile("global_load_dwordx4 %0, %1, off sc0 sc1\n\ts_waitcnt vmcnt(0)"
               : "=v"(r) : "v"(p) : "memory");
  return r;
}
// Dual coherent 16B loads, latencies overlapped.
__device__ __forceinline__ void ld_sc16x2(const unsigned* p0, const unsigned* p1,
                                          uint4& r0, uint4& r1) {
  asm volatile("global_load_dwordx4 %0, %2, off sc0 sc1\n\t"
               "global_load_dwordx4 %1, %3, off sc0 sc1\n\t"
               "s_waitcnt vmcnt(0)"
               : "=v"(r0), "=v"(r1) : "v"(p0), "v"(p1) : "memory");
}

__device__ __forceinline__ float fsigmoid(float x) {
  return __builtin_amdgcn_rcpf(1.f + __expf(-x));
}
__device__ __forceinline__ float ftanh(float x) {
  return 2.f * __builtin_amdgcn_rcpf(1.f + __expf(-2.f * x)) - 1.f;
}

// ---------------- GEMM: C[M][N] = A[M][K] @ B[N][K]^T + (b1+b2)[N] ----------------
// Only needed for layer 0 now (x @ W_ih0^T); layer-1's x-GEMM is fused into lstm_rec2.
__global__ __launch_bounds__(256, 2) void gemm_bias(
    const float* __restrict__ A, const float* __restrict__ B,
    const float* __restrict__ b1, const float* __restrict__ b2,
    float* __restrict__ C)
{
  const int N = 8192, K = 2048;
  __shared__ float As[32][68];
  __shared__ float Bs[32][68];
  const int tid = threadIdx.x;
  const int tx = tid & 15, ty = tid >> 4;
  const int row0 = blockIdx.y * 64, col0 = blockIdx.x * 64;
  const int lk = (tid & 7) * 4, lr = tid >> 3;
  float acc[4][4] = {};
  for (int k0 = 0; k0 < K; k0 += 32) {
    float4 a0 = *(const float4*)&A[(size_t)(row0 + lr)      * K + k0 + lk];
    float4 a1 = *(const float4*)&A[(size_t)(row0 + lr + 32) * K + k0 + lk];
    float4 bb0 = *(const float4*)&B[(size_t)(col0 + lr)      * K + k0 + lk];
    float4 bb1 = *(const float4*)&B[(size_t)(col0 + lr + 32) * K + k0 + lk];
    __syncthreads();
    As[lk+0][lr] = a0.x;  As[lk+1][lr] = a0.y;  As[lk+2][lr] = a0.z;  As[lk+3][lr] = a0.w;
    As[lk+0][lr+32] = a1.x; As[lk+1][lr+32] = a1.y; As[lk+2][lr+32] = a1.z; As[lk+3][lr+32] = a1.w;
    Bs[lk+0][lr] = bb0.x; Bs[lk+1][lr] = bb0.y; Bs[lk+2][lr] = bb0.z; Bs[lk+3][lr] = bb0.w;
    Bs[lk+0][lr+32] = bb1.x; Bs[lk+1][lr+32] = bb1.y; Bs[lk+2][lr+32] = bb1.z; Bs[lk+3][lr+32] = bb1.w;
    __syncthreads();
    #pragma unroll
    for (int kk = 0; kk < 32; ++kk) {
      float4 av = *(const float4*)&As[kk][ty * 4];
      float4 bv = *(const float4*)&Bs[kk][tx * 4];
      float am[4] = {av.x, av.y, av.z, av.w};
      float bm[4] = {bv.x, bv.y, bv.z, bv.w};
      #pragma unroll
      for (int i = 0; i < 4; ++i)
        #pragma unroll
        for (int j = 0; j < 4; ++j)
          acc[i][j] = fmaf(am[i], bm[j], acc[i][j]);
    }
  }
  #pragma unroll
  for (int i = 0; i < 4; ++i) {
    const int r = row0 + ty * 4 + i;
    #pragma unroll
    for (int j = 0; j < 4; ++j) {
      const int cc = col0 + tx * 4 + j;
      C[(size_t)r * N + cc] = acc[i][j] + b1[cc] + b2[cc];
    }
  }
}

// ---------------- Fused 2-layer persistent recurrent kernel ----------------
// 256 WGs x 512 threads, 1 WG/CU (same residency as the single-layer version).
// Wave w of WG b owns hidden index j = 8b+w for BOTH layers. Pipeline skew 1:
// iteration r runs layer-0 step r, publishes h0 row r ASAP, then runs layer-1
// step r-1 off the critical chain (its x-input is the h0 row already polled
// into LDS this iteration). Serial handoffs: 2049 instead of 4096, and the
// layer-1 input GEMM is folded into the W_ih1 dot (weights resident as f16).
__global__ __launch_bounds__(512, 2) void lstm_rec2(
    const float* __restrict__ Whh0,  // [8192][2048] layer 0
    const float* __restrict__ Wih1,  // [8192][2048] layer 1
    const float* __restrict__ Whh1,  // [8192][2048] layer 1
    const float* __restrict__ G,     // [T][8192] layer-0 x-contribution + biases
    const float* __restrict__ bih1, const float* __restrict__ bhh1,  // [8192]
    const float* __restrict__ h0v,   // [2][2048]
    const float* __restrict__ c0v,   // [2][2048]
    unsigned* HbufP0, unsigned* HbufP1,  // [T+1][2048] packed tagged
    float* __restrict__ hn, float* __restrict__ cn)  // [2][2048]
{
  const int b = blockIdx.x;
  const int tid = threadIdx.x;
  const int w = tid >> 6;
  const int lane = tid & 63;
  const int j = b * 8 + w;
  __shared__ unsigned hs0[2][HID / 2];
  __shared__ unsigned hs1[2][HID / 2];

  // Weight fragments: lane holds elems {2*lane,2*lane+1}+128*it of rows g*2048+j,
  // packed f32->f16 pairs. 3 matrices x 64 VGPRs = 192 VGPRs.
  h2_t wreg0[4][16], wregI[4][16], wregH[4][16];
  #pragma unroll
  for (int g = 0; g < 4; ++g) {
    const float* r0 = Whh0 + (size_t)(g * 2048 + j) * 2048 + 2 * lane;
    #pragma unroll
    for (int it = 0; it < 16; ++it) {
      float2 v = *(const float2*)(r0 + 128 * it);
      wreg0[g][it] = pk2(v.x, v.y);
    }
  }
  #pragma unroll
  for (int g = 0; g < 4; ++g) {
    const float* rI = Wih1 + (size_t)(g * 2048 + j) * 2048 + 2 * lane;
    #pragma unroll
    for (int it = 0; it < 16; ++it) {
      float2 v = *(const float2*)(rI + 128 * it);
      wregI[g][it] = pk2(v.x, v.y);
    }
  }
  #pragma unroll
  for (int g = 0; g < 4; ++g) {
    const float* rH = Whh1 + (size_t)(g * 2048 + j) * 2048 + 2 * lane;
    #pragma unroll
    for (int it = 0; it < 16; ++it) {
      float2 v = *(const float2*)(rH + 128 * it);
      wregH[g][it] = pk2(v.x, v.y);
    }
  }
  float bias1[4];
  #pragma unroll
  for (int g = 0; g < 4; ++g)
    bias1[g] = bih1[g * 2048 + j] + bhh1[g * 2048 + j];

  float c0val = c0v[j];
  float c1val = c0v[HID + j];
  float h0last = 0.f, h1last = 0.f;

  // Publish row 0 (initial h) for both layers, tag 0.
  if (tid < 8) {
    __hip_atomic_store(&HbufP0[b * 8 + tid], pkh(h0v[b * 8 + tid], 0u),
                       __ATOMIC_RELAXED, __HIP_MEMORY_SCOPE_AGENT);
    __hip_atomic_store(&HbufP1[b * 8 + tid], pkh(h0v[HID + b * 8 + tid], 0u),
                       __ATOMIC_RELAXED, __HIP_MEMORY_SCOPE_AGENT);
  }

  for (int r = 1; r <= T_LEN + 1; ++r) {
    const bool doL0 = (r <= T_LEN);
    // Prefetch this step's G values (overlaps the gather wait).
    float gpre = (doL0 && lane < 4) ? G[(size_t)(r - 1) * G4 + lane * 2048 + j] : 0.f;

    const unsigned want0 = (unsigned)(r - 1);
    const unsigned* src0 = HbufP0 + (size_t)(r - 1) * HID + 4 * tid;
    uint4 u0, u1;
    if (r >= 2) {
      const unsigned want1 = (unsigned)(r - 2);
      const unsigned* src1 = HbufP1 + (size_t)(r - 2) * HID + 4 * tid;
      ld_sc16x2(src0, src1, u0, u1);   // overlap both poll latencies
      int sp = 0;
      while (!(((u1.x >> 16) == want1) & ((u1.y >> 16) == want1) &
               ((u1.z >> 16) == want1) & ((u1.w >> 16) == want1))) {
        if (++sp > 4) __builtin_amdgcn_s_sleep(1);
        if (sp > (1 << 20)) break;
        u1 = ld_sc16(src1);
      }
      unsigned* row1 = hs1[r & 1];
      *(uint2*)&row1[2 * tid] = make_uint2((u1.x & 0xffffu) | (u1.y << 16),
                                           (u1.z & 0xffffu) | (u1.w << 16));
    } else {
      u0 = ld_sc16(src0);
    }
    {
      int sp = 0;
      while (!(((u0.x >> 16) == want0) & ((u0.y >> 16) == want0) &
               ((u0.z >> 16) == want0) & ((u0.w >> 16) == want0))) {
        if (++sp > 4) __builtin_amdgcn_s_sleep(1);
        if (sp > (1 << 20)) break;
        u0 = ld_sc16(src0);
      }
    }
    unsigned* row0 = hs0[r & 1];
    *(uint2*)&row0[2 * tid] = make_uint2((u0.x & 0xffffu) | (u0.y << 16),
                                         (u0.z & 0xffffu) | (u0.w << 16));
    __syncthreads();

    // ---- Layer 0 step r (critical chain) ----
    if (doL0) {
      const unsigned* hr = hs0[r & 1];
      float a0 = 0.f, a1 = 0.f, a2 = 0.f, a3 = 0.f;
      #pragma unroll
      for (int it = 0; it < 16; ++it) {
        h2_t hv = __builtin_bit_cast(h2_t, hr[lane + 64 * it]);
        a0 = __builtin_amdgcn_fdot2(wreg0[0][it], hv, a0, false);
        a1 = __builtin_amdgcn_fdot2(wreg0[1][it], hv, a1, false);
        a2 = __builtin_amdgcn_fdot2(wreg0[2][it], hv, a2, false);
        a3 = __builtin_amdgcn_fdot2(wreg0[3][it], hv, a3, false);
      }
      #pragma unroll
      for (int off = 32; off > 0; off >>= 1) {
        a0 += __shfl_xor(a0, off, 64);
        a1 += __shfl_xor(a1, off, 64);
        a2 += __shfl_xor(a2, off, 64);
        a3 += __shfl_xor(a3, off, 64);
      }
      float g0 = __shfl(gpre, 0, 64), g1 = __shfl(gpre, 1, 64);
      float g2 = __shfl(gpre, 2, 64), g3 = __shfl(gpre, 3, 64);
      float ig = fsigmoid(a0 + g0);
      float fg = fsigmoid(a1 + g1);
      float gg = ftanh(a2 + g2);
      float og = fsigmoid(a3 + g3);
      c0val = fg * c0val + ig * gg;
      h0last = og * ftanh(c0val);
      if (lane == 0)
        __hip_atomic_store(&HbufP0[(size_t)r * HID + j], pkh(h0last, (unsigned)r),
                           __ATOMIC_RELAXED, __HIP_MEMORY_SCOPE_AGENT);
    }

    // ---- Layer 1 step r-1 (off the chain; x-input = hs0 polled this iter) ----
    if (r >= 2) {
      const unsigned* xr = hs0[r & 1];
      const unsigned* hr = hs1[r & 1];
      float a0 = 0.f, a1 = 0.f, a2 = 0.f, a3 = 0.f;
      #pragma unroll
      for (int it = 0; it < 16; ++it) {
        h2_t xv = __builtin_bit_cast(h2_t, xr[lane + 64 * it]);
        a0 = __builtin_amdgcn_fdot2(wregI[0][it], xv, a0, false);
        a1 = __builtin_amdgcn_fdot2(wregI[1][it], xv, a1, false);
        a2 = __builtin_amdgcn_fdot2(wregI[2][it], xv, a2, false);
        a3 = __builtin_amdgcn_fdot2(wregI[3][it], xv, a3, false);
        h2_t hv = __builtin_bit_cast(h2_t, hr[lane + 64 * it]);
        a0 = __builtin_amdgcn_fdot2(wregH[0][it], hv, a0, false);
        a1 = __builtin_amdgcn_fdot2(wregH[1][it], hv, a1, false);
        a2 = __builtin_amdgcn_fdot2(wregH[2][it], hv, a2, false);
        a3 = __builtin_amdgcn_fdot2(wregH[3][it], hv, a3, false);
      }
      #pragma unroll
      for (int off = 32; off > 0; off >>= 1) {
        a0 += __shfl_xor(a0, off, 64);
        a1 += __shfl_xor(a1, off, 64);
        a2 += __shfl_xor(a2, off, 64);
        a3 += __shfl_xor(a3, off, 64);
      }
      float ig = fsigmoid(a0 + bias1[0]);
      float fg = fsigmoid(a1 + bias1[1]);
      float gg = ftanh(a2 + bias1[2]);
      float og = fsigmoid(a3 + bias1[3]);
      c1val = fg * c1val + ig * gg;
      h1last = og * ftanh(c1val);
      if (lane == 0)
        __hip_atomic_store(&HbufP1[(size_t)(r - 1) * HID + j],
                           pkh(h1last, (unsigned)(r - 1)),
                           __ATOMIC_RELAXED, __HIP_MEMORY_SCOPE_AGENT);
    }
  }
  if (lane == 0) {
    hn[j] = h0last;       cn[j] = c0val;
    hn[HID + j] = h1last; cn[HID + j] = c1val;
  }
}

// ---------------- FC + log_softmax ----------------
__global__ __launch_bounds__(128) void fc_lsm(
    const unsigned* __restrict__ Hrows,  // [T][2048] packed (HbufP1 + HID)
    const float* __restrict__ fcw,       // [128][2048]
    const float* __restrict__ fcb,       // [128]
    float* __restrict__ out)             // [T][128]
{
  const int t = blockIdx.x;
  const int v = threadIdx.x;
  __shared__ float hs[HID];
  __shared__ float red[4];
  const unsigned* hrow = Hrows + (size_t)t * HID;
  for (int q = v; q < HID / 4; q += 128) {
    uint4 uv = *(const uint4*)&hrow[q * 4];
    hs[q * 4 + 0] = uph(uv.x); hs[q * 4 + 1] = uph(uv.y);
    hs[q * 4 + 2] = uph(uv.z); hs[q * 4 + 3] = uph(uv.w);
  }
  __syncthreads();
  const float* wrow = fcw + (size_t)v * HID;
  float acc = fcb[v];
  #pragma unroll 4
  for (int k = 0; k < HID; k += 4) {
    float4 wv = *(const float4*)&wrow[k];
    acc = fmaf(wv.x, hs[k],     acc);
    acc = fmaf(wv.y, hs[k + 1], acc);
    acc = fmaf(wv.z, hs[k + 2], acc);
    acc = fmaf(wv.w, hs[k + 3], acc);
  }
  float m = acc;
  #pragma unroll
  for (int off = 32; off > 0; off >>= 1) m = fmaxf(m, __shfl_xor(m, off, 64));
  if ((v & 63) == 0) red[v >> 6] = m;
  __syncthreads();
  m = fmaxf(red[0], red[1]);
  float e = expf(acc - m), s = e;
  #pragma unroll
  for (int off = 32; off > 0; off >>= 1) s += __shfl_xor(s, off, 64);
  if ((v & 63) == 0) red[2 + (v >> 6)] = s;
  __syncthreads();
  s = red[2] + red[3];
  out[(size_t)t * NV + v] = (acc - m) - logf(s);
}

extern "C" void kernel_launch(void* const* d_in, const int* in_sizes, int n_in,
                              void* d_out, int out_size, void* d_ws, size_t ws_size,
                              hipStream_t stream) {
  const float* x   = (const float*)d_in[0];
  const float* h0  = (const float*)d_in[1];
  const float* c0  = (const float*)d_in[2];
  const float* Wih = (const float*)d_in[3];
  const float* Whh = (const float*)d_in[4];
  const float* bih = (const float*)d_in[5];
  const float* bhh = (const float*)d_in[6];
  const float* fcw = (const float*)d_in[7];
  const float* fcb = (const float*)d_in[8];
  float* out = (float*)d_out;

  // ws layout (bytes): G 67,108,864 | HbufP0 16,785,408 | HbufP1 16,785,408
  char* ws = (char*)d_ws;
  float*    G      = (float*)(ws);
  unsigned* HbufP0 = (unsigned*)(ws + 67108864);
  unsigned* HbufP1 = (unsigned*)(ws + 67108864 + 16785408);

  dim3 ggrid(G4 / 64, T_LEN / 64);  // (128, 32)

  // Layer-0 x-contribution GEMM (layer-1's is fused into lstm_rec2).
  gemm_bias<<<ggrid, 256, 0, stream>>>(x, Wih, bih, bhh, G);
  // Fused 2-layer pipelined recurrence.
  lstm_rec2<<<256, 512, 0, stream>>>(Whh, Wih + (size_t)G4 * HID,
                                     Whh + (size_t)G4 * HID, G,
                                     bih + G4, bhh + G4, h0, c0,
                                     HbufP0, HbufP1,
                                     out + 262144, out + 266240);
  // FC + log_softmax on layer-1 outputs.
  fc_lsm<<<T_LEN, 128, 0, stream>>>(HbufP1 + HID, fcw, fcb, out);
}